// Round 5
// baseline (228.569 us; speedup 1.0000x reference)
//
#include <hip/hip_runtime.h>
#include <math.h>

#define NT 256
#define NBSPLIT 4
#define NB (16 / NBSPLIT)
#define NSWEEPS 4

__device__ __forceinline__ float fsqrt_(float x) { return __builtin_amdgcn_sqrtf(x); }
__device__ __forceinline__ float frcp_(float x)  { return __builtin_amdgcn_rcpf(x); }
__device__ __forceinline__ float frsq_(float x)  { return __builtin_amdgcn_rsqf(x); }

// One cyclic-Jacobi rotation on symmetric 3x3 (pivot (p,q), remaining index r).
__device__ __forceinline__ void jrot(float& app, float& aqq, float& apq,
                                     float& arp, float& arq,
                                     float& vp0, float& vp1, float& vp2,
                                     float& vq0, float& vq1, float& vq2)
{
    float a = apq;
    float scale = fabsf(app) + fabsf(aqq);
    if (fabsf(a) > 1e-12f * scale + 1e-35f) {
        float tau = (aqq - app) * 0.5f * frcp_(a);
        float den = fabsf(tau) + fsqrt_(1.0f + tau * tau);
        float t = frcp_(den);
        t = (tau < 0.0f) ? -t : t;
        float c = frsq_(1.0f + t * t);
        float s = t * c;
        app -= t * a;
        aqq += t * a;
        apq = 0.0f;
        float rp = arp, rq = arq;
        arp = c * rp - s * rq;
        arq = s * rp + c * rq;
        float x, y;
        x = vp0; y = vq0; vp0 = c * x - s * y; vq0 = s * x + c * y;
        x = vp1; y = vq1; vp1 = c * x - s * y; vq1 = s * x + c * y;
        x = vp2; y = vq2; vp2 = c * x - s * y; vq2 = s * x + c * y;
    }
}

// Specialized maxd==6 kernel: one thread = one vertex, iterates NB batches.
// Persistent register cache: jo(6) + wgt(6) + tvc(18) = 30 regs.
// tevw is NOT loaded: tevw[v,k,d] == adj_w[v,k] * tevT[v,d,k] (folded).
// Edges are NOT cached across passes (round-4 lesson: that pushed the peak
// live-set to ~100 and __launch_bounds__(,6) spilled it). Pass 2 re-gathers
// from L1/L2 (batch pred slice = 1.2 MB, L2-resident).
// __launch_bounds__(256,5): soft cap ~100 VGPR, ~20 above expected need.
__global__ __launch_bounds__(NT, 5) void arap_fused6(
    const float* __restrict__ pred,      // (B, 3, n)
    const int*   __restrict__ adj_idx,   // (n, 6)
    const float* __restrict__ adj_w,     // (n, 6)
    const float* __restrict__ tevT,      // (n, 3, 6)
    float* __restrict__ partials,        // (B, nblk_x)
    int n, int nblk_x)
{
    const int v = blockIdx.x * NT + threadIdx.x;
    const bool active = (v < n);
    const int vc = active ? v : 0;
    const int b0 = blockIdx.y * NB;

    // ---- cache per-vertex adjacency data in registers (read ONCE) ----
    int   jo[6];
    float wgt[6];
    float tvc[18];   // tevT row: (3,6) contiguous
    {
        const int2* ai = (const int2*)(adj_idx + (size_t)vc * 6);
        int2 q0 = ai[0], q1 = ai[1], q2 = ai[2];
        jo[0] = q0.x; jo[1] = q0.y; jo[2] = q1.x;
        jo[3] = q1.y; jo[4] = q2.x; jo[5] = q2.y;
        const float2* aw = (const float2*)(adj_w + (size_t)vc * 6);
        float2 w0 = aw[0], w1 = aw[1], w2 = aw[2];
        wgt[0] = w0.x; wgt[1] = w0.y; wgt[2] = w1.x;
        wgt[3] = w1.y; wgt[4] = w2.x; wgt[5] = w2.y;
        const float2* tv = (const float2*)(tevT + (size_t)vc * 18);
        #pragma unroll
        for (int i = 0; i < 9; ++i) { float2 t = tv[i]; tvc[2*i] = t.x; tvc[2*i+1] = t.y; }
    }

    __shared__ float sm[NT / 64][NB];
    const int lane = threadIdx.x & 63, wid = threadIdx.x >> 6;

    #pragma unroll 1   // keep body inside I$; no bi-indexed register arrays
    for (int bi = 0; bi < NB; ++bi) {
        const float* __restrict__ predb = pred + (size_t)(b0 + bi) * 3 * n;
        const float p0x = predb[vc];
        const float p0y = predb[n + vc];
        const float p0z = predb[2 * n + vc];

        // Pass 1: A = 1000 * pred_ev (3x6) @ tev_w (6x3), tev_w = w*tevT.
        float a00 = 0.f, a01 = 0.f, a02 = 0.f;
        float a10 = 0.f, a11 = 0.f, a12 = 0.f;
        float a20 = 0.f, a21 = 0.f, a22 = 0.f;
        #pragma unroll
        for (int k = 0; k < 6; ++k) {
            int j = jo[k];
            float exk = predb[j]         - p0x;
            float eyk = predb[n + j]     - p0y;
            float ezk = predb[2 * n + j] - p0z;
            float t0 = tvc[k], t1 = tvc[6 + k], t2 = tvc[12 + k];
            float w = wgt[k];
            float fx = w * exk, fy = w * eyk, fz = w * ezk;
            a00 += fx * t0; a01 += fx * t1; a02 += fx * t2;
            a10 += fy * t0; a11 += fy * t1; a12 += fy * t2;
            a20 += fz * t0; a21 += fz * t1; a22 += fz * t2;
        }
        const float stab = 1000.0f;
        a00 *= stab; a01 *= stab; a02 *= stab;
        a10 *= stab; a11 *= stab; a12 *= stab;
        a20 *= stab; a21 *= stab; a22 *= stab;

        // M = A^T A (symmetric)
        float m00 = a00 * a00 + a10 * a10 + a20 * a20;
        float m01 = a00 * a01 + a10 * a11 + a20 * a21;
        float m02 = a00 * a02 + a10 * a12 + a20 * a22;
        float m11 = a01 * a01 + a11 * a11 + a21 * a21;
        float m12 = a01 * a02 + a11 * a12 + a21 * a22;
        float m22 = a02 * a02 + a12 * a12 + a22 * a22;

        // Jacobi eigendecomposition
        float v00 = 1.f, v01 = 0.f, v02 = 0.f;
        float v10 = 0.f, v11 = 1.f, v12 = 0.f;
        float v20 = 0.f, v21 = 0.f, v22 = 1.f;
        #pragma unroll
        for (int sweep = 0; sweep < NSWEEPS; ++sweep) {
            jrot(m00, m11, m01, m02, m12, v00, v10, v20, v01, v11, v21);
            jrot(m00, m22, m02, m01, m12, v00, v10, v20, v02, v12, v22);
            jrot(m11, m22, m12, m01, m02, v01, v11, v21, v02, v12, v22);
        }

        // U = A V / S
        float is0 = frsq_(fmaxf(m00, 1e-6f));
        float is1 = frsq_(fmaxf(m11, 1e-6f));
        float is2 = frsq_(fmaxf(m22, 1e-6f));
        float u00 = (a00 * v00 + a01 * v10 + a02 * v20) * is0;
        float u10 = (a10 * v00 + a11 * v10 + a12 * v20) * is0;
        float u20 = (a20 * v00 + a21 * v10 + a22 * v20) * is0;
        float u01 = (a00 * v01 + a01 * v11 + a02 * v21) * is1;
        float u11 = (a10 * v01 + a11 * v11 + a12 * v21) * is1;
        float u21 = (a20 * v01 + a21 * v11 + a22 * v21) * is1;
        float u02 = (a00 * v02 + a01 * v12 + a02 * v22) * is2;
        float u12 = (a10 * v02 + a11 * v12 + a12 * v22) * is2;
        float u22 = (a20 * v02 + a21 * v12 + a22 * v22) * is2;

        // Rt = U V^T
        float r00 = u00 * v00 + u01 * v01 + u02 * v02;
        float r01 = u00 * v10 + u01 * v11 + u02 * v12;
        float r02 = u00 * v20 + u01 * v21 + u02 * v22;
        float r10 = u10 * v00 + u11 * v01 + u12 * v02;
        float r11 = u10 * v10 + u11 * v11 + u12 * v12;
        float r12 = u10 * v20 + u11 * v21 + u12 * v22;
        float r20 = u20 * v00 + u21 * v01 + u22 * v02;
        float r21 = u20 * v10 + u21 * v11 + u22 * v12;
        float r22 = u20 * v20 + u21 * v21 + u22 * v22;

        float dd = r00 * (r11 * r22 - r21 * r12)
                 - r10 * (r01 * r22 - r21 * r02)
                 + r20 * (r01 * r12 - r11 * r02);

        // det fix on largest-eigenvalue column
        float lm = m00;
        float ux = u00, uy = u10, uz = u20;
        float wx = v00, wy = v10, wz = v20;
        if (m11 > lm) { lm = m11; ux = u01; uy = u11; uz = u21; wx = v01; wy = v11; wz = v21; }
        if (m22 > lm) { lm = m22; ux = u02; uy = u12; uz = u22; wx = v02; wy = v12; wz = v22; }
        float e = dd - 1.0f;
        r00 += e * ux * wx; r01 += e * ux * wy; r02 += e * ux * wz;
        r10 += e * uy * wx; r11 += e * uy * wy; r12 += e * uy * wz;
        r20 += e * uz * wx; r21 += e * uz * wy; r22 += e * uz * wz;

        // Pass 2: energy — re-gather neighbor edges (L1/L2 hits)
        float nrg = 0.0f;
        #pragma unroll
        for (int k = 0; k < 6; ++k) {
            int j = jo[k];
            float exk = predb[j]         - p0x;
            float eyk = predb[n + j]     - p0y;
            float ezk = predb[2 * n + j] - p0z;
            float tv0 = tvc[k], tv1 = tvc[6 + k], tv2 = tvc[12 + k];
            float q0 = r00 * tv0 + r01 * tv1 + r02 * tv2;
            float q1 = r10 * tv0 + r11 * tv1 + r12 * tv2;
            float q2 = r20 * tv0 + r21 * tv1 + r22 * tv2;
            float dx = exk - q0, dy = eyk - q1, dz = ezk - q2;
            nrg += wgt[k] * fsqrt_(dx * dx + dy * dy + dz * dz);
        }
        float val = active ? fminf(nrg, 1.0f) : 0.0f;

        // immediate wave reduction -> LDS (no per-b register accumulators)
        #pragma unroll
        for (int off = 32; off > 0; off >>= 1)
            val += __shfl_down(val, off, 64);
        if (lane == 0) sm[wid][bi] = val;
    }

    __syncthreads();
    if (threadIdx.x < NB) {
        float s = 0.0f;
        #pragma unroll
        for (int w = 0; w < NT / 64; ++w) s += sm[w][threadIdx.x];
        partials[(size_t)(b0 + threadIdx.x) * nblk_x + blockIdx.x] = s;
    }
}

// ---------------- generic fallback ----------------
__global__ __launch_bounds__(NT) void arap_main(
    const float* __restrict__ pred, const int* __restrict__ adj_idx,
    const float* __restrict__ adj_w, const float* __restrict__ tevT,
    const float* __restrict__ tevw, float* __restrict__ partials,
    int n, int maxd, int nblk_x)
{
    const int b = blockIdx.y;
    const float* __restrict__ predb = pred + (size_t)b * 3 * n;
    float local = 0.0f;

    for (int v = blockIdx.x * NT + threadIdx.x; v < n; v += nblk_x * NT) {
        const float p0x = predb[v];
        const float p0y = predb[n + v];
        const float p0z = predb[2 * n + v];

        float a00 = 0.f, a01 = 0.f, a02 = 0.f;
        float a10 = 0.f, a11 = 0.f, a12 = 0.f;
        float a20 = 0.f, a21 = 0.f, a22 = 0.f;
        for (int k = 0; k < maxd; ++k) {
            int j = adj_idx[v * maxd + k];
            float ex = predb[j] - p0x;
            float ey = predb[n + j] - p0y;
            float ez = predb[2 * n + j] - p0z;
            const float* tw = tevw + ((size_t)v * maxd + k) * 3;
            float t0 = tw[0], t1 = tw[1], t2 = tw[2];
            a00 += ex * t0; a01 += ex * t1; a02 += ex * t2;
            a10 += ey * t0; a11 += ey * t1; a12 += ey * t2;
            a20 += ez * t0; a21 += ez * t1; a22 += ez * t2;
        }
        const float stab = 1000.0f;
        a00 *= stab; a01 *= stab; a02 *= stab;
        a10 *= stab; a11 *= stab; a12 *= stab;
        a20 *= stab; a21 *= stab; a22 *= stab;

        float m00 = a00 * a00 + a10 * a10 + a20 * a20;
        float m01 = a00 * a01 + a10 * a11 + a20 * a21;
        float m02 = a00 * a02 + a10 * a12 + a20 * a22;
        float m11 = a01 * a01 + a11 * a11 + a21 * a21;
        float m12 = a01 * a02 + a11 * a12 + a21 * a22;
        float m22 = a02 * a02 + a12 * a12 + a22 * a22;

        float v00 = 1.f, v01 = 0.f, v02 = 0.f;
        float v10 = 0.f, v11 = 1.f, v12 = 0.f;
        float v20 = 0.f, v21 = 0.f, v22 = 1.f;
        #pragma unroll
        for (int sweep = 0; sweep < NSWEEPS; ++sweep) {
            jrot(m00, m11, m01, m02, m12, v00, v10, v20, v01, v11, v21);
            jrot(m00, m22, m02, m01, m12, v00, v10, v20, v02, v12, v22);
            jrot(m11, m22, m12, m01, m02, v01, v11, v21, v02, v12, v22);
        }

        float is0 = frsq_(fmaxf(m00, 1e-6f));
        float is1 = frsq_(fmaxf(m11, 1e-6f));
        float is2 = frsq_(fmaxf(m22, 1e-6f));
        float u00 = (a00 * v00 + a01 * v10 + a02 * v20) * is0;
        float u10 = (a10 * v00 + a11 * v10 + a12 * v20) * is0;
        float u20 = (a20 * v00 + a21 * v10 + a22 * v20) * is0;
        float u01 = (a00 * v01 + a01 * v11 + a02 * v21) * is1;
        float u11 = (a10 * v01 + a11 * v11 + a12 * v21) * is1;
        float u21 = (a20 * v01 + a21 * v11 + a22 * v21) * is1;
        float u02 = (a00 * v02 + a01 * v12 + a02 * v22) * is2;
        float u12 = (a10 * v02 + a11 * v12 + a12 * v22) * is2;
        float u22 = (a20 * v02 + a21 * v12 + a22 * v22) * is2;

        float r00 = u00 * v00 + u01 * v01 + u02 * v02;
        float r01 = u00 * v10 + u01 * v11 + u02 * v12;
        float r02 = u00 * v20 + u01 * v21 + u02 * v22;
        float r10 = u10 * v00 + u11 * v01 + u12 * v02;
        float r11 = u10 * v10 + u11 * v11 + u12 * v12;
        float r12 = u10 * v20 + u11 * v21 + u12 * v22;
        float r20 = u20 * v00 + u21 * v01 + u22 * v02;
        float r21 = u20 * v10 + u21 * v11 + u22 * v12;
        float r22 = u20 * v20 + u21 * v21 + u22 * v22;

        float dd = r00 * (r11 * r22 - r21 * r12)
                 - r10 * (r01 * r22 - r21 * r02)
                 + r20 * (r01 * r12 - r11 * r02);

        float lm = m00;
        float ux = u00, uy = u10, uz = u20;
        float wx = v00, wy = v10, wz = v20;
        if (m11 > lm) { lm = m11; ux = u01; uy = u11; uz = u21; wx = v01; wy = v11; wz = v21; }
        if (m22 > lm) { lm = m22; ux = u02; uy = u12; uz = u22; wx = v02; wy = v12; wz = v22; }
        float e = dd - 1.0f;
        r00 += e * ux * wx; r01 += e * ux * wy; r02 += e * ux * wz;
        r10 += e * uy * wx; r11 += e * uy * wy; r12 += e * uy * wz;
        r20 += e * uz * wx; r21 += e * uz * wy; r22 += e * uz * wz;

        float nrg = 0.0f;
        const float* tvb = tevT + (size_t)v * 3 * maxd;
        for (int k = 0; k < maxd; ++k) {
            int j = adj_idx[v * maxd + k];
            float w = adj_w[v * maxd + k];
            float ex = predb[j] - p0x;
            float ey = predb[n + j] - p0y;
            float ez = predb[2 * n + j] - p0z;
            float tv0 = tvb[k];
            float tv1 = tvb[maxd + k];
            float tv2 = tvb[2 * maxd + k];
            float q0 = r00 * tv0 + r01 * tv1 + r02 * tv2;
            float q1 = r10 * tv0 + r11 * tv1 + r12 * tv2;
            float q2 = r20 * tv0 + r21 * tv1 + r22 * tv2;
            float dx = ex - q0, dy = ey - q1, dz = ez - q2;
            nrg += w * fsqrt_(dx * dx + dy * dy + dz * dz);
        }
        local += fminf(nrg, 1.0f);
    }

    float val = local;
    for (int off = 32; off > 0; off >>= 1)
        val += __shfl_down(val, off, 64);
    __shared__ float smf[NT / 64];
    int lane = threadIdx.x & 63, wid = threadIdx.x >> 6;
    if (lane == 0) smf[wid] = val;
    __syncthreads();
    if (threadIdx.x == 0)
        partials[(size_t)b * nblk_x + blockIdx.x] = smf[0] + smf[1] + smf[2] + smf[3];
}

__global__ __launch_bounds__(NT) void arap_reduce(
    const float* __restrict__ partials, float* __restrict__ out,
    int nblk_x, float inv_n)
{
    int b = blockIdx.x;
    float val = 0.0f;
    for (int i = threadIdx.x; i < nblk_x; i += NT)
        val += partials[(size_t)b * nblk_x + i];
    for (int off = 32; off > 0; off >>= 1)
        val += __shfl_down(val, off, 64);
    __shared__ float smf[NT / 64];
    int lane = threadIdx.x & 63, wid = threadIdx.x >> 6;
    if (lane == 0) smf[wid] = val;
    __syncthreads();
    if (threadIdx.x == 0)
        out[b] = (smf[0] + smf[1] + smf[2] + smf[3]) * inv_n;
}

extern "C" void kernel_launch(void* const* d_in, const int* in_sizes, int n_in,
                              void* d_out, int out_size, void* d_ws, size_t ws_size,
                              hipStream_t stream)
{
    const float* pred    = (const float*)d_in[0];
    const int*   adj_idx = (const int*)d_in[1];
    const float* adj_w   = (const float*)d_in[2];
    const float* tevT    = (const float*)d_in[3];
    const float* tevw    = (const float*)d_in[4];
    float* out = (float*)d_out;

    const int B = 16;
    const int n = in_sizes[0] / (3 * B);
    const int maxd = in_sizes[1] / n;

    int nblk_full = (n + NT - 1) / NT;
    int ws_floats = (int)(ws_size / sizeof(float));
    float* partials = (float*)d_ws;

    if (maxd == 6 && (long long)nblk_full * B <= ws_floats) {
        dim3 grid(nblk_full, NBSPLIT);
        arap_fused6<<<grid, NT, 0, stream>>>(pred, adj_idx, adj_w, tevT,
                                             partials, n, nblk_full);
        arap_reduce<<<B, NT, 0, stream>>>(partials, out, nblk_full,
                                          1.0f / (float)n);
    } else {
        int nblk_x = nblk_full;
        if ((long long)nblk_x * B > ws_floats) nblk_x = ws_floats / B;
        if (nblk_x < 1) nblk_x = 1;
        dim3 grid(nblk_x, B);
        arap_main<<<grid, NT, 0, stream>>>(pred, adj_idx, adj_w, tevT, tevw,
                                           partials, n, maxd, nblk_x);
        arap_reduce<<<B, NT, 0, stream>>>(partials, out, nblk_x,
                                          1.0f / (float)n);
    }
}

// Round 6
// 53.180 us; speedup vs baseline: 4.2980x; 4.2980x over previous
//
#include <hip/hip_runtime.h>
#include <math.h>

#define NT 256
#define NBSPLIT 4
#define NB (16 / NBSPLIT)
#define NSWEEPS 4

__device__ __forceinline__ float fsqrt_(float x) { return __builtin_amdgcn_sqrtf(x); }
__device__ __forceinline__ float frcp_(float x)  { return __builtin_amdgcn_rcpf(x); }
__device__ __forceinline__ float frsq_(float x)  { return __builtin_amdgcn_rsqf(x); }

// One cyclic-Jacobi rotation on symmetric 3x3 (pivot (p,q), remaining index r).
__device__ __forceinline__ void jrot(float& app, float& aqq, float& apq,
                                     float& arp, float& arq,
                                     float& vp0, float& vp1, float& vp2,
                                     float& vq0, float& vq1, float& vq2)
{
    float a = apq;
    float scale = fabsf(app) + fabsf(aqq);
    if (fabsf(a) > 1e-12f * scale + 1e-35f) {
        float tau = (aqq - app) * 0.5f * frcp_(a);
        float den = fabsf(tau) + fsqrt_(1.0f + tau * tau);
        float t = frcp_(den);
        t = (tau < 0.0f) ? -t : t;
        float c = frsq_(1.0f + t * t);
        float s = t * c;
        app -= t * a;
        aqq += t * a;
        apq = 0.0f;
        float rp = arp, rq = arq;
        arp = c * rp - s * rq;
        arq = s * rp + c * rq;
        float x, y;
        x = vp0; y = vq0; vp0 = c * x - s * y; vq0 = s * x + c * y;
        x = vp1; y = vq1; vp1 = c * x - s * y; vq1 = s * x + c * y;
        x = vp2; y = vq2; vp2 = c * x - s * y; vq2 = s * x + c * y;
    }
}

// maxd==6 specialized. One thread = one vertex, iterates NB batches.
// VGPR-pressure design (target <=64 -> 8 waves/SIMD, per m69 64/128 steps):
//  - tevT row lives in LDS [18][NT] (thread-private column: lane-stride 1
//    word = conflict-free, NO barriers needed). Frees 18 VGPRs.
//  - tevw never loaded: tevw[v,k,:] == adj_w[v,k] * tevT[v,:,k] (folded).
//  - U never materialized: R = A * W, W = V diag(is0,is1,is2*d_at_argmax) V^T
//    (symmetric, 6 regs). d = det(A)*is0*is1*is2 == det(Rt) exactly.
//  - pass 2 re-gathers edges from L1/L2 instead of caching (rounds 4/5
//    lesson: launch_bounds min-waves pin => catastrophic spill; NO pin here).
__global__ __launch_bounds__(NT) void arap_fused6(
    const float* __restrict__ pred,      // (B, 3, n)
    const int*   __restrict__ adj_idx,   // (n, 6)
    const float* __restrict__ adj_w,     // (n, 6)
    const float* __restrict__ tevT,      // (n, 3, 6)
    float* __restrict__ partials,        // (B, nblk_x)
    int n, int nblk_x)
{
    __shared__ float tvs[18][NT];        // 18.4 KB: 8 blocks/CU still fits
    __shared__ float sm[NT / 64][NB];

    const int tid = threadIdx.x;
    const int v = blockIdx.x * NT + tid;
    const bool active = (v < n);
    const int vc = active ? v : 0;
    const int b0 = blockIdx.y * NB;

    int   jo[6];
    float wgt[6];
    {
        const int2* ai = (const int2*)(adj_idx + (size_t)vc * 6);
        int2 q0 = ai[0], q1 = ai[1], q2 = ai[2];
        jo[0] = q0.x; jo[1] = q0.y; jo[2] = q1.x;
        jo[3] = q1.y; jo[4] = q2.x; jo[5] = q2.y;
        const float2* aw = (const float2*)(adj_w + (size_t)vc * 6);
        float2 w0 = aw[0], w1 = aw[1], w2 = aw[2];
        wgt[0] = w0.x; wgt[1] = w0.y; wgt[2] = w1.x;
        wgt[3] = w1.y; wgt[4] = w2.x; wgt[5] = w2.y;
        const float2* tv = (const float2*)(tevT + (size_t)vc * 18);
        #pragma unroll
        for (int i = 0; i < 9; ++i) {
            float2 t = tv[i];
            tvs[2 * i][tid]     = t.x;
            tvs[2 * i + 1][tid] = t.y;
        }
        // no __syncthreads: each thread only ever reads its own column
    }

    const int lane = tid & 63, wid = tid >> 6;

    #pragma unroll 1
    for (int bi = 0; bi < NB; ++bi) {
        const float* __restrict__ predb = pred + (size_t)(b0 + bi) * 3 * n;
        const float p0x = predb[vc];
        const float p0y = predb[n + vc];
        const float p0z = predb[2 * n + vc];

        // Pass 1: A = 1000 * pred_ev (3x6) @ (w * tevT^T) (6x3)
        float a00 = 0.f, a01 = 0.f, a02 = 0.f;
        float a10 = 0.f, a11 = 0.f, a12 = 0.f;
        float a20 = 0.f, a21 = 0.f, a22 = 0.f;
        #pragma unroll
        for (int k = 0; k < 6; ++k) {
            int j = jo[k];
            float exk = predb[j]         - p0x;
            float eyk = predb[n + j]     - p0y;
            float ezk = predb[2 * n + j] - p0z;
            float t0 = tvs[k][tid], t1 = tvs[6 + k][tid], t2 = tvs[12 + k][tid];
            float w = wgt[k];
            float fx = w * exk, fy = w * eyk, fz = w * ezk;
            a00 += fx * t0; a01 += fx * t1; a02 += fx * t2;
            a10 += fy * t0; a11 += fy * t1; a12 += fy * t2;
            a20 += fz * t0; a21 += fz * t1; a22 += fz * t2;
        }
        const float stab = 1000.0f;
        a00 *= stab; a01 *= stab; a02 *= stab;
        a10 *= stab; a11 *= stab; a12 *= stab;
        a20 *= stab; a21 *= stab; a22 *= stab;

        // M = A^T A (symmetric)
        float m00 = a00 * a00 + a10 * a10 + a20 * a20;
        float m01 = a00 * a01 + a10 * a11 + a20 * a21;
        float m02 = a00 * a02 + a10 * a12 + a20 * a22;
        float m11 = a01 * a01 + a11 * a11 + a21 * a21;
        float m12 = a01 * a02 + a11 * a12 + a21 * a22;
        float m22 = a02 * a02 + a12 * a12 + a22 * a22;

        // Jacobi eigendecomposition: M -> diag(m00,m11,m22), V accumulated
        float v00 = 1.f, v01 = 0.f, v02 = 0.f;
        float v10 = 0.f, v11 = 1.f, v12 = 0.f;
        float v20 = 0.f, v21 = 0.f, v22 = 1.f;
        #pragma unroll
        for (int sweep = 0; sweep < NSWEEPS; ++sweep) {
            jrot(m00, m11, m01, m02, m12, v00, v10, v20, v01, v11, v21);
            jrot(m00, m22, m02, m01, m12, v00, v10, v20, v02, v12, v22);
            jrot(m11, m22, m12, m01, m02, v01, v11, v21, v02, v12, v22);
        }

        // is_k = 1/sqrt(max(lambda_k,1e-6)); det-fix folded into argmax col
        float is0 = frsq_(fmaxf(m00, 1e-6f));
        float is1 = frsq_(fmaxf(m11, 1e-6f));
        float is2 = frsq_(fmaxf(m22, 1e-6f));
        float detA = a00 * (a11 * a22 - a21 * a12)
                   - a10 * (a01 * a22 - a21 * a02)
                   + a20 * (a01 * a12 - a11 * a02);
        float dd = detA * is0 * is1 * is2;   // == det(Rt) exactly
        bool c2 = (m22 >= m00) && (m22 >= m11);
        bool c1 = !c2 && (m11 >= m00);
        bool c0 = !c2 && !c1;
        is0 = c0 ? is0 * dd : is0;
        is1 = c1 ? is1 * dd : is1;
        is2 = c2 ? is2 * dd : is2;

        // W = V diag(is) V^T (symmetric)
        float w00 = is0 * v00 * v00 + is1 * v01 * v01 + is2 * v02 * v02;
        float w01 = is0 * v00 * v10 + is1 * v01 * v11 + is2 * v02 * v12;
        float w02 = is0 * v00 * v20 + is1 * v01 * v21 + is2 * v02 * v22;
        float w11 = is0 * v10 * v10 + is1 * v11 * v11 + is2 * v12 * v12;
        float w12 = is0 * v10 * v20 + is1 * v11 * v21 + is2 * v12 * v22;
        float w22 = is0 * v20 * v20 + is1 * v21 * v21 + is2 * v22 * v22;

        // R = A W
        float r00 = a00 * w00 + a01 * w01 + a02 * w02;
        float r01 = a00 * w01 + a01 * w11 + a02 * w12;
        float r02 = a00 * w02 + a01 * w12 + a02 * w22;
        float r10 = a10 * w00 + a11 * w01 + a12 * w02;
        float r11 = a10 * w01 + a11 * w11 + a12 * w12;
        float r12 = a10 * w02 + a11 * w12 + a12 * w22;
        float r20 = a20 * w00 + a21 * w01 + a22 * w02;
        float r21 = a20 * w01 + a21 * w11 + a22 * w12;
        float r22 = a20 * w02 + a21 * w12 + a22 * w22;

        // Pass 2: energy — re-gather edges (L1/L2 hits)
        float nrg = 0.0f;
        #pragma unroll
        for (int k = 0; k < 6; ++k) {
            int j = jo[k];
            float exk = predb[j]         - p0x;
            float eyk = predb[n + j]     - p0y;
            float ezk = predb[2 * n + j] - p0z;
            float t0 = tvs[k][tid], t1 = tvs[6 + k][tid], t2 = tvs[12 + k][tid];
            float q0 = r00 * t0 + r01 * t1 + r02 * t2;
            float q1 = r10 * t0 + r11 * t1 + r12 * t2;
            float q2 = r20 * t0 + r21 * t1 + r22 * t2;
            float dx = exk - q0, dy = eyk - q1, dz = ezk - q2;
            nrg += wgt[k] * fsqrt_(dx * dx + dy * dy + dz * dz);
        }
        float val = active ? fminf(nrg, 1.0f) : 0.0f;

        #pragma unroll
        for (int off = 32; off > 0; off >>= 1)
            val += __shfl_down(val, off, 64);
        if (lane == 0) sm[wid][bi] = val;
    }

    __syncthreads();
    if (tid < NB) {
        float s = 0.0f;
        #pragma unroll
        for (int w = 0; w < NT / 64; ++w) s += sm[w][tid];
        partials[(size_t)(b0 + tid) * nblk_x + blockIdx.x] = s;
    }
}

// ---------------- generic fallback ----------------
__global__ __launch_bounds__(NT) void arap_main(
    const float* __restrict__ pred, const int* __restrict__ adj_idx,
    const float* __restrict__ adj_w, const float* __restrict__ tevT,
    const float* __restrict__ tevw, float* __restrict__ partials,
    int n, int maxd, int nblk_x)
{
    const int b = blockIdx.y;
    const float* __restrict__ predb = pred + (size_t)b * 3 * n;
    float local = 0.0f;

    for (int v = blockIdx.x * NT + threadIdx.x; v < n; v += nblk_x * NT) {
        const float p0x = predb[v];
        const float p0y = predb[n + v];
        const float p0z = predb[2 * n + v];

        float a00 = 0.f, a01 = 0.f, a02 = 0.f;
        float a10 = 0.f, a11 = 0.f, a12 = 0.f;
        float a20 = 0.f, a21 = 0.f, a22 = 0.f;
        for (int k = 0; k < maxd; ++k) {
            int j = adj_idx[v * maxd + k];
            float ex = predb[j] - p0x;
            float ey = predb[n + j] - p0y;
            float ez = predb[2 * n + j] - p0z;
            const float* tw = tevw + ((size_t)v * maxd + k) * 3;
            float t0 = tw[0], t1 = tw[1], t2 = tw[2];
            a00 += ex * t0; a01 += ex * t1; a02 += ex * t2;
            a10 += ey * t0; a11 += ey * t1; a12 += ey * t2;
            a20 += ez * t0; a21 += ez * t1; a22 += ez * t2;
        }
        const float stab = 1000.0f;
        a00 *= stab; a01 *= stab; a02 *= stab;
        a10 *= stab; a11 *= stab; a12 *= stab;
        a20 *= stab; a21 *= stab; a22 *= stab;

        float m00 = a00 * a00 + a10 * a10 + a20 * a20;
        float m01 = a00 * a01 + a10 * a11 + a20 * a21;
        float m02 = a00 * a02 + a10 * a12 + a20 * a22;
        float m11 = a01 * a01 + a11 * a11 + a21 * a21;
        float m12 = a01 * a02 + a11 * a12 + a21 * a22;
        float m22 = a02 * a02 + a12 * a12 + a22 * a22;

        float v00 = 1.f, v01 = 0.f, v02 = 0.f;
        float v10 = 0.f, v11 = 1.f, v12 = 0.f;
        float v20 = 0.f, v21 = 0.f, v22 = 1.f;
        #pragma unroll
        for (int sweep = 0; sweep < NSWEEPS; ++sweep) {
            jrot(m00, m11, m01, m02, m12, v00, v10, v20, v01, v11, v21);
            jrot(m00, m22, m02, m01, m12, v00, v10, v20, v02, v12, v22);
            jrot(m11, m22, m12, m01, m02, v01, v11, v21, v02, v12, v22);
        }

        float is0 = frsq_(fmaxf(m00, 1e-6f));
        float is1 = frsq_(fmaxf(m11, 1e-6f));
        float is2 = frsq_(fmaxf(m22, 1e-6f));
        float detA = a00 * (a11 * a22 - a21 * a12)
                   - a10 * (a01 * a22 - a21 * a02)
                   + a20 * (a01 * a12 - a11 * a02);
        float dd = detA * is0 * is1 * is2;
        bool c2 = (m22 >= m00) && (m22 >= m11);
        bool c1 = !c2 && (m11 >= m00);
        bool c0 = !c2 && !c1;
        is0 = c0 ? is0 * dd : is0;
        is1 = c1 ? is1 * dd : is1;
        is2 = c2 ? is2 * dd : is2;

        float w00 = is0 * v00 * v00 + is1 * v01 * v01 + is2 * v02 * v02;
        float w01 = is0 * v00 * v10 + is1 * v01 * v11 + is2 * v02 * v12;
        float w02 = is0 * v00 * v20 + is1 * v01 * v21 + is2 * v02 * v22;
        float w11 = is0 * v10 * v10 + is1 * v11 * v11 + is2 * v12 * v12;
        float w12 = is0 * v10 * v20 + is1 * v11 * v21 + is2 * v12 * v22;
        float w22 = is0 * v20 * v20 + is1 * v21 * v21 + is2 * v22 * v22;

        float r00 = a00 * w00 + a01 * w01 + a02 * w02;
        float r01 = a00 * w01 + a01 * w11 + a02 * w12;
        float r02 = a00 * w02 + a01 * w12 + a02 * w22;
        float r10 = a10 * w00 + a11 * w01 + a12 * w02;
        float r11 = a10 * w01 + a11 * w11 + a12 * w12;
        float r12 = a10 * w02 + a11 * w12 + a12 * w22;
        float r20 = a20 * w00 + a21 * w01 + a22 * w02;
        float r21 = a20 * w01 + a21 * w11 + a22 * w12;
        float r22 = a20 * w02 + a21 * w12 + a22 * w22;

        float nrg = 0.0f;
        const float* tvb = tevT + (size_t)v * 3 * maxd;
        for (int k = 0; k < maxd; ++k) {
            int j = adj_idx[v * maxd + k];
            float w = adj_w[v * maxd + k];
            float ex = predb[j] - p0x;
            float ey = predb[n + j] - p0y;
            float ez = predb[2 * n + j] - p0z;
            float tv0 = tvb[k];
            float tv1 = tvb[maxd + k];
            float tv2 = tvb[2 * maxd + k];
            float q0 = r00 * tv0 + r01 * tv1 + r02 * tv2;
            float q1 = r10 * tv0 + r11 * tv1 + r12 * tv2;
            float q2 = r20 * tv0 + r21 * tv1 + r22 * tv2;
            float dx = ex - q0, dy = ey - q1, dz = ez - q2;
            nrg += w * fsqrt_(dx * dx + dy * dy + dz * dz);
        }
        local += fminf(nrg, 1.0f);
    }

    float val = local;
    for (int off = 32; off > 0; off >>= 1)
        val += __shfl_down(val, off, 64);
    __shared__ float smf[NT / 64];
    int lane = threadIdx.x & 63, wid = threadIdx.x >> 6;
    if (lane == 0) smf[wid] = val;
    __syncthreads();
    if (threadIdx.x == 0)
        partials[(size_t)b * nblk_x + blockIdx.x] = smf[0] + smf[1] + smf[2] + smf[3];
}

__global__ __launch_bounds__(NT) void arap_reduce(
    const float* __restrict__ partials, float* __restrict__ out,
    int nblk_x, float inv_n)
{
    int b = blockIdx.x;
    float val = 0.0f;
    for (int i = threadIdx.x; i < nblk_x; i += NT)
        val += partials[(size_t)b * nblk_x + i];
    for (int off = 32; off > 0; off >>= 1)
        val += __shfl_down(val, off, 64);
    __shared__ float smf[NT / 64];
    int lane = threadIdx.x & 63, wid = threadIdx.x >> 6;
    if (lane == 0) smf[wid] = val;
    __syncthreads();
    if (threadIdx.x == 0)
        out[b] = (smf[0] + smf[1] + smf[2] + smf[3]) * inv_n;
}

extern "C" void kernel_launch(void* const* d_in, const int* in_sizes, int n_in,
                              void* d_out, int out_size, void* d_ws, size_t ws_size,
                              hipStream_t stream)
{
    const float* pred    = (const float*)d_in[0];
    const int*   adj_idx = (const int*)d_in[1];
    const float* adj_w   = (const float*)d_in[2];
    const float* tevT    = (const float*)d_in[3];
    const float* tevw    = (const float*)d_in[4];
    float* out = (float*)d_out;

    const int B = 16;
    const int n = in_sizes[0] / (3 * B);
    const int maxd = in_sizes[1] / n;

    int nblk_full = (n + NT - 1) / NT;
    int ws_floats = (int)(ws_size / sizeof(float));
    float* partials = (float*)d_ws;

    if (maxd == 6 && (long long)nblk_full * B <= ws_floats) {
        dim3 grid(nblk_full, NBSPLIT);
        arap_fused6<<<grid, NT, 0, stream>>>(pred, adj_idx, adj_w, tevT,
                                             partials, n, nblk_full);
        arap_reduce<<<B, NT, 0, stream>>>(partials, out, nblk_full,
                                          1.0f / (float)n);
    } else {
        int nblk_x = nblk_full;
        if ((long long)nblk_x * B > ws_floats) nblk_x = ws_floats / B;
        if (nblk_x < 1) nblk_x = 1;
        dim3 grid(nblk_x, B);
        arap_main<<<grid, NT, 0, stream>>>(pred, adj_idx, adj_w, tevT, tevw,
                                           partials, n, maxd, nblk_x);
        arap_reduce<<<B, NT, 0, stream>>>(partials, out, nblk_x,
                                          1.0f / (float)n);
    }
}